// Round 2
// baseline (307.104 us; speedup 1.0000x reference)
//
#include <hip/hip_runtime.h>

// Dims: B=64, C=512, NE=80, NI=20, E=512. All fp32 (per reference).
// One block per column c. 256 threads = 16(tx: output neuron) x 16(ty: batch).
// Each thread: acc_e[4][5] covering b = ty+16*ib, o = tx+16*io (NE=80=5*16),
//              acc_i[4][2] covering o_i = tx+16*io (valid o_i < 20).

typedef unsigned int u32;

__global__ __launch_bounds__(256) void ei_cols_f32(
    const float* __restrict__ thal,     // [64][512]
    const float* __restrict__ inc,      // [64][512][512]
    const float* __restrict__ l23,      // [64][512][80]
    const float* __restrict__ re_in,    // [64][512][80]
    const float* __restrict__ ri_in,    // [64][512][20]
    const float* __restrict__ ev_in,    // [64][512][80]
    const float* __restrict__ iv_in,    // [64][512][20]
    const float* __restrict__ in_proj,  // [512][80][512]
    const float* __restrict__ fb_proj,  // [512][80][80]
    const float* __restrict__ w_ee,     // [512][80][80]
    const float* __restrict__ w_ei,     // [512][20][80]
    const float* __restrict__ w_ie,     // [512][80][20]
    float* __restrict__ out)            // r_e|r_i|v_e|v_i flat (fp32)
{
  __shared__ __align__(16) float smem[14784];  // 59136 B max (phase C)
  const int c = blockIdx.x;
  const int tid = threadIdx.x;
  const int tx = tid & 15;
  const int ty = tid >> 4;

  float acc_e[4][5];
  float acc_i[4][2];
#pragma unroll
  for (int ib = 0; ib < 4; ++ib) {
#pragma unroll
    for (int io = 0; io < 5; ++io) acc_e[ib][io] = 0.f;
    acc_i[ib][0] = 0.f;
    acc_i[ib][1] = 0.f;
  }

  // ---------------- Phase A: I_ext = (thal + inc) . in_proj^T, K=512 -------
  {
    float* As = smem;         // [64][68]
    float* Ws = smem + 4352;  // [80][68]
    for (int k0 = 0; k0 < 512; k0 += 64) {
      __syncthreads();
      for (int l = tid; l < 1024; l += 256) {
        int b = l >> 4, kk = (l & 15) << 2;
        float4 tv = *(const float4*)(thal + b * 512 + k0 + kk);
        float4 iv = *(const float4*)(inc + (size_t)b * 262144 + (size_t)c * 512 + k0 + kk);
        float4 s;
        s.x = tv.x + iv.x; s.y = tv.y + iv.y; s.z = tv.z + iv.z; s.w = tv.w + iv.w;
        *(float4*)(As + b * 68 + kk) = s;
      }
      for (int l = tid; l < 1280; l += 256) {
        int o = l >> 4, kk = (l & 15) << 2;
        *(float4*)(Ws + o * 68 + kk) =
            *(const float4*)(in_proj + (size_t)c * 40960 + o * 512 + k0 + kk);
      }
      __syncthreads();
#pragma unroll 4
      for (int kc = 0; kc < 64; kc += 4) {
        float4 av[4], wv[5];
#pragma unroll
        for (int ib = 0; ib < 4; ++ib)
          av[ib] = *(const float4*)(As + (ty + 16 * ib) * 68 + kc);
#pragma unroll
        for (int io = 0; io < 5; ++io)
          wv[io] = *(const float4*)(Ws + (tx + 16 * io) * 68 + kc);
#pragma unroll
        for (int ib = 0; ib < 4; ++ib)
#pragma unroll
          for (int io = 0; io < 5; ++io) {
            float a = acc_e[ib][io];
            a = fmaf(av[ib].x, wv[io].x, a);
            a = fmaf(av[ib].y, wv[io].y, a);
            a = fmaf(av[ib].z, wv[io].z, a);
            a = fmaf(av[ib].w, wv[io].w, a);
            acc_e[ib][io] = a;
          }
      }
    }
  }

  // ---------------- Phase B: I_fb = l23 . fb_proj^T, K=80 ------------------
  {
    __syncthreads();
    float* As = smem;         // [64][84]
    float* Bs = smem + 5376;  // [80][84]
    for (int l = tid; l < 1280; l += 256) {
      int b = l / 20, kk = (l % 20) << 2;
      *(float4*)(As + b * 84 + kk) =
          *(const float4*)(l23 + ((size_t)b * 512 + c) * 80 + kk);
    }
    for (int l = tid; l < 1600; l += 256) {
      int o = l / 20, kk = (l % 20) << 2;
      *(float4*)(Bs + o * 84 + kk) =
          *(const float4*)(fb_proj + ((size_t)c * 80 + o) * 80 + kk);
    }
    __syncthreads();
#pragma unroll 4
    for (int kc = 0; kc < 80; kc += 4) {
      float4 av[4], wv[5];
#pragma unroll
      for (int ib = 0; ib < 4; ++ib)
        av[ib] = *(const float4*)(As + (ty + 16 * ib) * 84 + kc);
#pragma unroll
      for (int io = 0; io < 5; ++io)
        wv[io] = *(const float4*)(Bs + (tx + 16 * io) * 84 + kc);
#pragma unroll
      for (int ib = 0; ib < 4; ++ib)
#pragma unroll
        for (int io = 0; io < 5; ++io) {
          float a = acc_e[ib][io];
          a = fmaf(av[ib].x, wv[io].x, a);
          a = fmaf(av[ib].y, wv[io].y, a);
          a = fmaf(av[ib].z, wv[io].z, a);
          a = fmaf(av[ib].w, wv[io].w, a);
          acc_e[ib][io] = a;
        }
    }
  }

  // ---------------- Phase C: I_ee = r_e.W_ee^T ; I_ei = r_e.W_ei^T ---------
  {
    __syncthreads();
    float* As = smem;          // [64][84] r_e
    float* W1 = smem + 5376;   // [80][84] W_ee
    float* W2 = smem + 12096;  // [32][84] W_ei (rows 20..31 zero)
    for (int l = tid; l < 1280; l += 256) {
      int b = l / 20, kk = (l % 20) << 2;
      *(float4*)(As + b * 84 + kk) =
          *(const float4*)(re_in + ((size_t)b * 512 + c) * 80 + kk);
    }
    for (int l = tid; l < 1600; l += 256) {
      int o = l / 20, kk = (l % 20) << 2;
      *(float4*)(W1 + o * 84 + kk) =
          *(const float4*)(w_ee + ((size_t)c * 80 + o) * 80 + kk);
    }
    for (int l = tid; l < 640; l += 256) {
      int o = l / 20, kk = (l % 20) << 2;
      float4 v = {0.f, 0.f, 0.f, 0.f};
      if (o < 20) v = *(const float4*)(w_ei + ((size_t)c * 20 + o) * 80 + kk);
      *(float4*)(W2 + o * 84 + kk) = v;
    }
    __syncthreads();
#pragma unroll 4
    for (int kc = 0; kc < 80; kc += 4) {
      float4 av[4], wv[5], w2[2];
#pragma unroll
      for (int ib = 0; ib < 4; ++ib)
        av[ib] = *(const float4*)(As + (ty + 16 * ib) * 84 + kc);
#pragma unroll
      for (int io = 0; io < 5; ++io)
        wv[io] = *(const float4*)(W1 + (tx + 16 * io) * 84 + kc);
#pragma unroll
      for (int io = 0; io < 2; ++io)
        w2[io] = *(const float4*)(W2 + (tx + 16 * io) * 84 + kc);
#pragma unroll
      for (int ib = 0; ib < 4; ++ib) {
#pragma unroll
        for (int io = 0; io < 5; ++io) {
          float a = acc_e[ib][io];
          a = fmaf(av[ib].x, wv[io].x, a);
          a = fmaf(av[ib].y, wv[io].y, a);
          a = fmaf(av[ib].z, wv[io].z, a);
          a = fmaf(av[ib].w, wv[io].w, a);
          acc_e[ib][io] = a;
        }
#pragma unroll
        for (int io = 0; io < 2; ++io) {
          float a = acc_i[ib][io];
          a = fmaf(av[ib].x, w2[io].x, a);
          a = fmaf(av[ib].y, w2[io].y, a);
          a = fmaf(av[ib].z, w2[io].z, a);
          a = fmaf(av[ib].w, w2[io].w, a);
          acc_i[ib][io] = a;
        }
      }
    }
  }

  // ---------------- Phase D: I_ie = r_i . (-W_ie)^T, K=20 ------------------
  {
    __syncthreads();
    float* Ri = smem;         // [64][28]
    float* Wn = smem + 1792;  // [80][28] negated W_ie
    for (int l = tid; l < 320; l += 256) {
      int b = l / 5, kk = (l % 5) << 2;
      *(float4*)(Ri + b * 28 + kk) =
          *(const float4*)(ri_in + ((size_t)b * 512 + c) * 20 + kk);
    }
    for (int l = tid; l < 400; l += 256) {
      int o = l / 5, kk = (l % 5) << 2;
      float4 v = *(const float4*)(w_ie + ((size_t)c * 80 + o) * 20 + kk);
      v.x = -v.x; v.y = -v.y; v.z = -v.z; v.w = -v.w;
      *(float4*)(Wn + o * 28 + kk) = v;
    }
    __syncthreads();
#pragma unroll
    for (int kc = 0; kc < 20; kc += 4) {
      float4 av[4], wv[5];
#pragma unroll
      for (int ib = 0; ib < 4; ++ib)
        av[ib] = *(const float4*)(Ri + (ty + 16 * ib) * 28 + kc);
#pragma unroll
      for (int io = 0; io < 5; ++io)
        wv[io] = *(const float4*)(Wn + (tx + 16 * io) * 28 + kc);
#pragma unroll
      for (int ib = 0; ib < 4; ++ib)
#pragma unroll
        for (int io = 0; io < 5; ++io) {
          float a = acc_e[ib][io];
          a = fmaf(av[ib].x, wv[io].x, a);
          a = fmaf(av[ib].y, wv[io].y, a);
          a = fmaf(av[ib].z, wv[io].z, a);
          a = fmaf(av[ib].w, wv[io].w, a);
          acc_e[ib][io] = a;
        }
    }
  }

  // ---------------- Epilogue: v = v + 0.1*(I - v) ; r = relu(v) ------------
  const size_t R_ri = 2621440u;
  const size_t R_ve = 3276800u;
  const size_t R_vi = 5898240u;
#pragma unroll
  for (int ib = 0; ib < 4; ++ib) {
    int b = ty + 16 * ib;
#pragma unroll
    for (int io = 0; io < 5; ++io) {
      int o = tx + 16 * io;
      size_t g = ((size_t)b * 512 + c) * 80 + o;
      float ev = ev_in[g];
      float v = ev + 0.1f * (acc_e[ib][io] - ev);
      out[g] = fmaxf(v, 0.f);
      out[R_ve + g] = v;
    }
#pragma unroll
    for (int io = 0; io < 2; ++io) {
      int oi = tx + 16 * io;
      if (oi < 20) {
        size_t g = ((size_t)b * 512 + c) * 20 + oi;
        float iv = iv_in[g];
        float v = iv + 0.1f * (acc_i[ib][io] - iv);
        out[R_ri + g] = fmaxf(v, 0.f);
        out[R_vi + g] = v;
      }
    }
  }
}

extern "C" void kernel_launch(void* const* d_in, const int* in_sizes, int n_in,
                              void* d_out, int out_size, void* d_ws, size_t ws_size,
                              hipStream_t stream) {
  const float* thal = (const float*)d_in[0];
  const float* inc = (const float*)d_in[1];
  const float* l23 = (const float*)d_in[2];
  const float* re = (const float*)d_in[3];
  const float* ri = (const float*)d_in[4];
  const float* ev = (const float*)d_in[5];
  const float* iv = (const float*)d_in[6];
  const float* in_proj = (const float*)d_in[7];
  const float* fb_proj = (const float*)d_in[8];
  const float* w_ee = (const float*)d_in[9];
  const float* w_ei = (const float*)d_in[10];
  const float* w_ie = (const float*)d_in[11];
  float* out = (float*)d_out;
  ei_cols_f32<<<dim3(512), dim3(256), 0, stream>>>(
      thal, inc, l23, re, ri, ev, iv, in_proj, fb_proj, w_ee, w_ei, w_ie, out);
}

// Round 4
// 257.881 us; speedup vs baseline: 1.1909x; 1.1909x over previous
//
#include <hip/hip_runtime.h>
#include <hip/hip_bf16.h>

typedef __attribute__((ext_vector_type(8))) short bf16x8;
typedef __attribute__((ext_vector_type(4))) float f32x4;
typedef unsigned short u16;
typedef unsigned int u32;

__device__ __forceinline__ u16 f2bf(float f) {
  __hip_bfloat16 h = __float2bfloat16(f);  // RNE
  u16 u;
  __builtin_memcpy(&u, &h, 2);
  return u;
}
__device__ __forceinline__ void cvt4_store(u16* dst, float4 v) {
  u16 rr[4] = {f2bf(v.x), f2bf(v.y), f2bf(v.z), f2bf(v.w)};
  uint2 p;
  __builtin_memcpy(&p, rr, 8);
  *(uint2*)dst = p;  // 8B-aligned by construction
}

// Dims: B=64, C=512, NE=80, NI=20, E=512. fp32 I/O, bf16 MFMA compute.
// One block per column. 4 waves x 16 batches. MFMA 16x16x32 gemm_bt layout:
//   a-frag A[m=lane&15][k=quad*8+j], b-frag Bt[n=lane&15][k=quad*8+j],
//   C/D:   C[m=quad*4+reg][n=lane&15]   (verified m89/m91 mapping)

__global__ __launch_bounds__(256) void ei_cols_mfma(
    const float* __restrict__ thal,     // [64][512]
    const float* __restrict__ inc,      // [64][512][512]
    const float* __restrict__ l23,      // [64][512][80]
    const float* __restrict__ re_in,    // [64][512][80]
    const float* __restrict__ ri_in,    // [64][512][20]
    const float* __restrict__ ev_in,    // [64][512][80]
    const float* __restrict__ iv_in,    // [64][512][20]
    const float* __restrict__ in_proj,  // [512][80][512]
    const float* __restrict__ fb_proj,  // [512][80][80]
    const float* __restrict__ w_ee,     // [512][80][80]
    const float* __restrict__ w_ei,     // [512][20][80]
    const float* __restrict__ w_ie,     // [512][80][20]
    float* __restrict__ out)            // r_e|r_i|v_e|v_i flat fp32
{
  __shared__ __align__(16) unsigned char smem[41472];
  const int c = blockIdx.x;
  const int tid = threadIdx.x;
  const int lane = tid & 63;
  const int wave = tid >> 6;
  const int nidx = lane & 15;
  const int quad = lane >> 4;
  const int m0 = wave * 16;

  f32x4 acc_e[5], acc_i[2];
#pragma unroll
  for (int j = 0; j < 5; ++j) acc_e[j] = (f32x4){0.f, 0.f, 0.f, 0.f};
#pragma unroll
  for (int j = 0; j < 2; ++j) acc_i[j] = (f32x4){0.f, 0.f, 0.f, 0.f};

  // ---- Phase A: I_ext = (thal+inc).in_proj^T, K=512, double-buffered -----
  // buffer parity p: A tile at smem + p*20736, W tile at smem + 9216 + p*20736
  {
    float4 tv[4], gv[4], wv[5];

    auto load_regs = [&](int k0) {
#pragma unroll
      for (int j = 0; j < 4; ++j) {
        int l = tid + j * 256;
        int b = l >> 4, kk = (l & 15) << 2;
        tv[j] = *(const float4*)(thal + b * 512 + k0 + kk);
        gv[j] = *(const float4*)(inc + (size_t)b * 262144 + (size_t)c * 512 + k0 + kk);
      }
#pragma unroll
      for (int j = 0; j < 5; ++j) {
        int l = tid + j * 256;
        int o = l >> 4, kk = (l & 15) << 2;
        wv[j] = *(const float4*)(in_proj + (size_t)c * 40960 + o * 512 + k0 + kk);
      }
    };
    auto store_buf = [&](int p) {
      u16* A = (u16*)(smem + p * 20736);
      u16* W = (u16*)(smem + 9216 + p * 20736);
#pragma unroll
      for (int j = 0; j < 4; ++j) {
        int l = tid + j * 256;
        int b = l >> 4, kk = (l & 15) << 2;
        float4 s;
        s.x = tv[j].x + gv[j].x; s.y = tv[j].y + gv[j].y;
        s.z = tv[j].z + gv[j].z; s.w = tv[j].w + gv[j].w;
        cvt4_store(A + b * 72 + kk, s);
      }
#pragma unroll
      for (int j = 0; j < 5; ++j) {
        int l = tid + j * 256;
        int o = l >> 4, kk = (l & 15) << 2;
        cvt4_store(W + o * 72 + kk, wv[j]);
      }
    };

    load_regs(0);
    store_buf(0);
    for (int i = 0; i < 8; ++i) {
      __syncthreads();
      if (i < 7) load_regs((i + 1) * 64);
      const int p = i & 1;
      u16* A = (u16*)(smem + p * 20736);
      u16* W = (u16*)(smem + 9216 + p * 20736);
#pragma unroll
      for (int kk0 = 0; kk0 < 64; kk0 += 32) {
        bf16x8 a = *(const bf16x8*)(A + (m0 + nidx) * 72 + kk0 + quad * 8);
#pragma unroll
        for (int j = 0; j < 5; ++j) {
          bf16x8 b = *(const bf16x8*)(W + (j * 16 + nidx) * 72 + kk0 + quad * 8);
          acc_e[j] = __builtin_amdgcn_mfma_f32_16x16x32_bf16(a, b, acc_e[j], 0, 0, 0);
        }
      }
      if (i < 7) store_buf((i + 1) & 1);
    }
  }

  // ---- Phase B: I_fb = l23 . fb_proj^T, K=80 (pad 96) --------------------
  {
    __syncthreads();
    u16* As = (u16*)smem;            // [64][104]
    u16* Bs = (u16*)(smem + 13312);  // [80][104]
    for (int l = tid; l < 1280; l += 256) {
      int b = l / 20, kk = (l % 20) << 2;
      cvt4_store(As + b * 104 + kk,
                 *(const float4*)(l23 + ((size_t)b * 512 + c) * 80 + kk));
    }
    for (int l = tid; l < 128; l += 256) {
      int b = l >> 1, off = 80 + (l & 1) * 8;
      *(uint4*)(As + b * 104 + off) = (uint4){0u, 0u, 0u, 0u};
    }
    for (int l = tid; l < 1600; l += 256) {
      int o = l / 20, kk = (l % 20) << 2;
      cvt4_store(Bs + o * 104 + kk,
                 *(const float4*)(fb_proj + ((size_t)c * 80 + o) * 80 + kk));
    }
    for (int l = tid; l < 160; l += 256) {
      int o = l >> 1, off = 80 + (l & 1) * 8;
      *(uint4*)(Bs + o * 104 + off) = (uint4){0u, 0u, 0u, 0u};
    }
    __syncthreads();
#pragma unroll
    for (int kk0 = 0; kk0 < 96; kk0 += 32) {
      bf16x8 a = *(const bf16x8*)(As + (m0 + nidx) * 104 + kk0 + quad * 8);
#pragma unroll
      for (int j = 0; j < 5; ++j) {
        bf16x8 b = *(const bf16x8*)(Bs + (j * 16 + nidx) * 104 + kk0 + quad * 8);
        acc_e[j] = __builtin_amdgcn_mfma_f32_16x16x32_bf16(a, b, acc_e[j], 0, 0, 0);
      }
    }
  }

  // ---- Phase C: I_ee = r_e.W_ee^T (->e) ; I_ei = r_e.W_ei^T (->i) --------
  {
    __syncthreads();
    u16* As = (u16*)smem;            // [64][104] r_e
    u16* W1 = (u16*)(smem + 13312);  // [80][104] W_ee
    u16* W2 = (u16*)(smem + 29952);  // [32][104] W_ei rows 20..31 zero
    for (int l = tid; l < 1280; l += 256) {
      int b = l / 20, kk = (l % 20) << 2;
      cvt4_store(As + b * 104 + kk,
                 *(const float4*)(re_in + ((size_t)b * 512 + c) * 80 + kk));
    }
    for (int l = tid; l < 128; l += 256) {
      int b = l >> 1, off = 80 + (l & 1) * 8;
      *(uint4*)(As + b * 104 + off) = (uint4){0u, 0u, 0u, 0u};
    }
    for (int l = tid; l < 1600; l += 256) {
      int o = l / 20, kk = (l % 20) << 2;
      cvt4_store(W1 + o * 104 + kk,
                 *(const float4*)(w_ee + ((size_t)c * 80 + o) * 80 + kk));
    }
    for (int l = tid; l < 160; l += 256) {
      int o = l >> 1, off = 80 + (l & 1) * 8;
      *(uint4*)(W1 + o * 104 + off) = (uint4){0u, 0u, 0u, 0u};
    }
    for (int l = tid; l < 400; l += 256) {
      int o = l / 20, kk = (l % 20) << 2;
      cvt4_store(W2 + o * 104 + kk,
                 *(const float4*)(w_ei + ((size_t)c * 20 + o) * 80 + kk));
    }
    for (int l = tid; l < 40; l += 256) {
      int o = l >> 1, off = 80 + (l & 1) * 8;
      *(uint4*)(W2 + o * 104 + off) = (uint4){0u, 0u, 0u, 0u};
    }
    for (int l = tid; l < 156; l += 256) {
      int o = 20 + l / 13, off = (l % 13) * 8;
      *(uint4*)(W2 + o * 104 + off) = (uint4){0u, 0u, 0u, 0u};
    }
    __syncthreads();
#pragma unroll
    for (int kk0 = 0; kk0 < 96; kk0 += 32) {
      bf16x8 a = *(const bf16x8*)(As + (m0 + nidx) * 104 + kk0 + quad * 8);
#pragma unroll
      for (int j = 0; j < 5; ++j) {
        bf16x8 b = *(const bf16x8*)(W1 + (j * 16 + nidx) * 104 + kk0 + quad * 8);
        acc_e[j] = __builtin_amdgcn_mfma_f32_16x16x32_bf16(a, b, acc_e[j], 0, 0, 0);
      }
#pragma unroll
      for (int j = 0; j < 2; ++j) {
        bf16x8 b = *(const bf16x8*)(W2 + (j * 16 + nidx) * 104 + kk0 + quad * 8);
        acc_i[j] = __builtin_amdgcn_mfma_f32_16x16x32_bf16(a, b, acc_i[j], 0, 0, 0);
      }
    }
  }

  // ---- Phase D: I_ie = r_i . (-W_ie)^T, K=20 (pad 32) --------------------
  {
    __syncthreads();
    u16* Ri = (u16*)smem;           // [64][40]
    u16* Wn = (u16*)(smem + 5120);  // [80][40] negated
    for (int l = tid; l < 320; l += 256) {
      int b = l / 5, kk = (l % 5) << 2;
      cvt4_store(Ri + b * 40 + kk,
                 *(const float4*)(ri_in + ((size_t)b * 512 + c) * 20 + kk));
    }
    for (int l = tid; l < 192; l += 256) {
      int b = l / 3, kk = 20 + (l % 3) * 4;
      *(uint2*)(Ri + b * 40 + kk) = (uint2){0u, 0u};
    }
    for (int l = tid; l < 400; l += 256) {
      int o = l / 5, kk = (l % 5) << 2;
      float4 v = *(const float4*)(w_ie + ((size_t)c * 80 + o) * 20 + kk);
      v.x = -v.x; v.y = -v.y; v.z = -v.z; v.w = -v.w;
      cvt4_store(Wn + o * 40 + kk, v);
    }
    for (int l = tid; l < 240; l += 256) {
      int o = l / 3, kk = 20 + (l % 3) * 4;
      *(uint2*)(Wn + o * 40 + kk) = (uint2){0u, 0u};
    }
    __syncthreads();
    {
      bf16x8 a = *(const bf16x8*)(Ri + (m0 + nidx) * 40 + quad * 8);
#pragma unroll
      for (int j = 0; j < 5; ++j) {
        bf16x8 b = *(const bf16x8*)(Wn + (j * 16 + nidx) * 40 + quad * 8);
        acc_e[j] = __builtin_amdgcn_mfma_f32_16x16x32_bf16(a, b, acc_e[j], 0, 0, 0);
      }
    }
  }

  // ---- Epilogue: v = v_old + 0.1*(I - v_old) ; r = relu(v) ---------------
  __syncthreads();
  float* aE = (float*)smem;            // [64][84]
  float* aI = (float*)(smem + 21504);  // [64][36]
#pragma unroll
  for (int j = 0; j < 5; ++j)
#pragma unroll
    for (int r = 0; r < 4; ++r)
      aE[(m0 + quad * 4 + r) * 84 + j * 16 + nidx] = acc_e[j][r];
#pragma unroll
  for (int j = 0; j < 2; ++j) {
    int col = j * 16 + nidx;
    if (col < 20) {
#pragma unroll
      for (int r = 0; r < 4; ++r)
        aI[(m0 + quad * 4 + r) * 36 + col] = acc_i[j][r];
    }
  }
  __syncthreads();

  const size_t R_ri = 2621440u;
  const size_t R_ve = 3276800u;
  const size_t R_vi = 5898240u;
  for (int l = tid; l < 1280; l += 256) {
    int b = l / 20, c2 = (l % 20) << 2;
    float4 a = *(const float4*)(aE + b * 84 + c2);
    size_t g = ((size_t)b * 512 + c) * 80 + c2;
    float4 ev = *(const float4*)(ev_in + g);
    float4 v, r;
    v.x = ev.x + 0.1f * (a.x - ev.x); r.x = fmaxf(v.x, 0.f);
    v.y = ev.y + 0.1f * (a.y - ev.y); r.y = fmaxf(v.y, 0.f);
    v.z = ev.z + 0.1f * (a.z - ev.z); r.z = fmaxf(v.z, 0.f);
    v.w = ev.w + 0.1f * (a.w - ev.w); r.w = fmaxf(v.w, 0.f);
    *(float4*)(out + g) = r;
    *(float4*)(out + R_ve + g) = v;
  }
  for (int l = tid; l < 320; l += 256) {
    int b = l / 5, c2 = (l % 5) << 2;
    float4 a = *(const float4*)(aI + b * 36 + c2);
    size_t g = ((size_t)b * 512 + c) * 20 + c2;
    float4 iv = *(const float4*)(iv_in + g);
    float4 v, r;
    v.x = iv.x + 0.1f * (a.x - iv.x); r.x = fmaxf(v.x, 0.f);
    v.y = iv.y + 0.1f * (a.y - iv.y); r.y = fmaxf(v.y, 0.f);
    v.z = iv.z + 0.1f * (a.z - iv.z); r.z = fmaxf(v.z, 0.f);
    v.w = iv.w + 0.1f * (a.w - iv.w); r.w = fmaxf(v.w, 0.f);
    *(float4*)(out + R_ri + g) = r;
    *(float4*)(out + R_vi + g) = v;
  }
}

extern "C" void kernel_launch(void* const* d_in, const int* in_sizes, int n_in,
                              void* d_out, int out_size, void* d_ws, size_t ws_size,
                              hipStream_t stream) {
  const float* thal = (const float*)d_in[0];
  const float* inc = (const float*)d_in[1];
  const float* l23 = (const float*)d_in[2];
  const float* re = (const float*)d_in[3];
  const float* ri = (const float*)d_in[4];
  const float* ev = (const float*)d_in[5];
  const float* iv = (const float*)d_in[6];
  const float* in_proj = (const float*)d_in[7];
  const float* fb_proj = (const float*)d_in[8];
  const float* w_ee = (const float*)d_in[9];
  const float* w_ei = (const float*)d_in[10];
  const float* w_ie = (const float*)d_in[11];
  float* out = (float*)d_out;
  ei_cols_mfma<<<dim3(512), dim3(256), 0, stream>>>(
      thal, inc, l23, re, ri, ev, iv, in_proj, fb_proj, w_ee, w_ei, w_ie, out);
}